// Round 9
// baseline (139.037 us; speedup 1.0000x reference)
//
#include <hip/hip_runtime.h>
#include <math.h>

// Problem: B=32, C=8, H=256, W=256. 256 independent (softmax-expectation +
// argmax) reductions over 65536-element fp32 heatmaps, then sum(ed)/B.
// 134 MB pure-READ traffic, zero reuse.
// R8 post-mortem: non-temporal loads broke the ~3.2 TB/s "read cap" (it was
// L1/L2 allocation policy, not a service limit): partial kernel ~42 -> ~35us.
// Under nt the effective latency is longer (cache-bypass), so per-wave MLP
// -- proven useless under the old cap (R5) -- should bind again. This round
// composes both: R5's volatile-asm 8-load cluster (progressive vmcnt) with
// the nt modifier on every load.

constexpr int HW    = 256 * 256;       // elements per (b,c) heatmap
constexpr int BLOCK = 256;             // 4 waves
constexpr int SPLIT = 16;              // blocks per heatmap
constexpr int CHUNK4 = (HW / 4) / SPLIT;        // float4s per chunk = 1024
constexpr int ITERS  = CHUNK4 / BLOCK;          // float4s per thread = 4

__global__ __launch_bounds__(BLOCK, 8) void dsnt_partial_kernel(
        const float* __restrict__ input,
        const float* __restrict__ target,
        unsigned long long* __restrict__ ws_pk,   // [nmap*SPLIT]
        float* __restrict__ ws_s,                 // [nmap*SPLIT]
        float* __restrict__ ws_sx,
        float* __restrict__ ws_sy)
{
    const int bc    = blockIdx.x >> 4;          // heatmap index
    const int chunk = blockIdx.x & (SPLIT - 1); // which sixteenth of it
    const int tid   = threadIdx.x;

    const float4* __restrict__ in4 =
        reinterpret_cast<const float4*>(input) + (size_t)bc * (HW / 4) + chunk * CHUNK4;
    const float4* __restrict__ tg4 =
        reinterpret_cast<const float4*>(target) + (size_t)bc * (HW / 4) + chunk * CHUNK4;

    // Thread's 4 float4s per array sit at byte offsets {0,4096,8192,12288}
    // from (base + tid*16). The 13-bit signed offset field covers +/-4095,
    // so use two mid-point bases per array with offsets -/+2048.
    const char* in_lo = (const char*)(in4 + tid) + 2048;    // -2048 -> +0, +2048 -> +4096
    const char* in_hi = (const char*)(in4 + tid) + 10240;   // -2048 -> +8192, +2048 -> +12288
    const char* tg_lo = (const char*)(tg4 + tid) + 2048;
    const char* tg_hi = (const char*)(tg4 + tid) + 10240;

    float4 v0, v1, v2, v3, t0, t1, t2, t3;
    // ALL 8 loads issued back-to-back, all non-temporal; volatile asm cannot
    // be sunk, split, or reordered. Early-clobber dests.
    asm volatile(
        "global_load_dwordx4 %0, %8, off offset:-2048 nt\n\t"   // v0 @ +0
        "global_load_dwordx4 %1, %9, off offset:-2048 nt\n\t"   // t0 @ +0
        "global_load_dwordx4 %2, %8, off offset:2048 nt\n\t"    // v1 @ +4096
        "global_load_dwordx4 %3, %9, off offset:2048 nt\n\t"    // t1
        "global_load_dwordx4 %4, %10, off offset:-2048 nt\n\t"  // v2 @ +8192
        "global_load_dwordx4 %5, %11, off offset:-2048 nt\n\t"  // t2
        "global_load_dwordx4 %6, %10, off offset:2048 nt\n\t"   // v3 @ +12288
        "global_load_dwordx4 %7, %11, off offset:2048 nt"       // t3
        : "=&v"(v0), "=&v"(t0), "=&v"(v1), "=&v"(t1),
          "=&v"(v2), "=&v"(t2), "=&v"(v3), "=&v"(t3)
        : "v"(in_lo), "v"(tg_lo), "v"(in_hi), "v"(tg_hi)
        : "memory");

    // online accumulators (no max-subtraction needed: inputs ~ N(0,1),
    // exp() range [e^-6, e^6], sum ~1e5 -- safe in fp32; softmax is
    // shift-invariant so this matches the stabilized reference)
    float s = 0.f, sx = 0.f, sy = 0.f;
    float bv = -INFINITY;       // target argmax value
    int   bi = 0x7FFFFFFF;      // target argmax flat index (within heatmap)

    const int fbase = 4 * chunk * CHUNK4;        // chunk's flat base index

#define DSNT_WAIT(N)                                                      \
    asm volatile("s_waitcnt vmcnt(" #N ")" ::: "memory");                 \
    __builtin_amdgcn_sched_barrier(0);

#define DSNT_STEP(V, T, OFF)                                              \
    {                                                                     \
        const int f = fbase + 4 * (tid + (OFF));                          \
        const float y  = (float)((f >> 8) + 1) * (1.0f / 256.0f);         \
        const float x0 = (float)((f & 255) + 1) * (1.0f / 256.0f);        \
        const float e0 = __expf(V.x);                                     \
        const float e1 = __expf(V.y);                                     \
        const float e2 = __expf(V.z);                                     \
        const float e3 = __expf(V.w);                                     \
        const float es = (e0 + e1) + (e2 + e3);                           \
        s  += es;                                                         \
        sy += es * y;                                                     \
        sx += e0 * x0                                                     \
            + e1 * (x0 + 1.0f / 256.0f)                                   \
            + e2 * (x0 + 2.0f / 256.0f)                                   \
            + e3 * (x0 + 3.0f / 256.0f);                                  \
        if (T.x > bv) { bv = T.x; bi = f; }                               \
        if (T.y > bv) { bv = T.y; bi = f + 1; }                           \
        if (T.z > bv) { bv = T.z; bi = f + 2; }                           \
        if (T.w > bv) { bv = T.w; bi = f + 3; }                           \
    }

    DSNT_WAIT(6) DSNT_STEP(v0, t0, 0 * BLOCK)   // v0,t0 landed; 6 in flight
    DSNT_WAIT(4) DSNT_STEP(v1, t1, 1 * BLOCK)
    DSNT_WAIT(2) DSNT_STEP(v2, t2, 2 * BLOCK)
    DSNT_WAIT(0) DSNT_STEP(v3, t3, 3 * BLOCK)
#undef DSNT_STEP
#undef DSNT_WAIT

    // pack (value, inverted index): target in [0,1) so float bits are
    // order-isomorphic; larger packed == larger value, ties -> smaller index
    unsigned long long pk =
        ((unsigned long long)__float_as_uint(bv) << 32) |
        (unsigned long long)(0xFFFFFFFFu - (unsigned)bi);

    // wave-level reduction (64 lanes)
    #pragma unroll
    for (int off = 32; off > 0; off >>= 1) {
        s  += __shfl_down(s, off);
        sx += __shfl_down(sx, off);
        sy += __shfl_down(sy, off);
        const unsigned long long opk = __shfl_down(pk, off);
        pk = (opk > pk) ? opk : pk;
    }

    // cross-wave reduction via LDS (4 waves)
    __shared__ float ls[4], lsx[4], lsy[4];
    __shared__ unsigned long long lpk[4];
    const int wave = tid >> 6;
    const int lane = tid & 63;
    if (lane == 0) {
        ls[wave]  = s;
        lsx[wave] = sx;
        lsy[wave] = sy;
        lpk[wave] = pk;
    }
    __syncthreads();

    if (tid == 0) {
        #pragma unroll
        for (int wv = 1; wv < 4; ++wv) {
            s  += ls[wv];
            sx += lsx[wv];
            sy += lsy[wv];
            pk = (lpk[wv] > pk) ? lpk[wv] : pk;
        }
        const int slot = blockIdx.x;   // == bc * SPLIT + chunk
        ws_s[slot]  = s;
        ws_sx[slot] = sx;
        ws_sy[slot] = sy;
        ws_pk[slot] = pk;
    }
}

// one block, 256 threads: thread bc combines its 16 chunks in fixed order
// (deterministic), computes ed, block-reduces, writes the scalar.
__global__ __launch_bounds__(256) void dsnt_final_kernel(
        const unsigned long long* __restrict__ ws_pk,
        const float* __restrict__ ws_s,
        const float* __restrict__ ws_sx,
        const float* __restrict__ ws_sy,
        float* __restrict__ out,
        int nmap)
{
    const int bc = threadIdx.x;
    float ed = 0.f;
    if (bc < nmap) {
        float s = 0.f, sx = 0.f, sy = 0.f;
        unsigned long long pk = 0ull;
        #pragma unroll
        for (int c = 0; c < SPLIT; ++c) {
            const int slot = bc * SPLIT + c;
            s  += ws_s[slot];
            sx += ws_sx[slot];
            sy += ws_sy[slot];
            const unsigned long long p = ws_pk[slot];
            pk = (p > pk) ? p : pk;
        }
        const unsigned bi = 0xFFFFFFFFu - (unsigned)(pk & 0xFFFFFFFFull);
        const float px = sx / s;
        const float py = sy / s;
        const float tx = (float)((bi & 255) + 1) * (1.0f / 256.0f);
        const float ty = (float)((bi >> 8) + 1) * (1.0f / 256.0f);
        const float dx = tx - px;
        const float dy = ty - py;
        ed = sqrtf(dx * dx + dy * dy);
    }

    // block reduction of ed over 256 threads
    #pragma unroll
    for (int off = 32; off > 0; off >>= 1)
        ed += __shfl_down(ed, off);

    __shared__ float led[4];
    const int wave = threadIdx.x >> 6;
    const int lane = threadIdx.x & 63;
    if (lane == 0) led[wave] = ed;
    __syncthreads();

    if (threadIdx.x == 0) {
        const float total = (led[0] + led[1]) + (led[2] + led[3]);
        out[0] = total * (1.0f / 32.0f);   // /B, B=32
    }
}

extern "C" void kernel_launch(void* const* d_in, const int* in_sizes, int n_in,
                              void* d_out, int out_size, void* d_ws, size_t ws_size,
                              hipStream_t stream) {
    const float* input  = (const float*)d_in[0];
    const float* target = (const float*)d_in[1];
    float* out = (float*)d_out;

    const int n_maps = in_sizes[0] / HW;   // B*C = 256
    const int nslot  = n_maps * SPLIT;     // 4096

    // workspace layout (all 8B-aligned; ~80 KB total):
    //   [0)        : u64 packed argmax, nslot
    //   [8*nslot)  : float s,  nslot
    //   [12*nslot) : float sx, nslot
    //   [16*nslot) : float sy, nslot
    unsigned long long* ws_pk = (unsigned long long*)d_ws;
    float* ws_s  = (float*)((char*)d_ws + (size_t)8  * nslot);
    float* ws_sx = (float*)((char*)d_ws + (size_t)12 * nslot);
    float* ws_sy = (float*)((char*)d_ws + (size_t)16 * nslot);

    // every (bc,chunk) slot is written unconditionally -> no memset needed;
    // final kernel overwrites the poisoned d_out directly.
    dsnt_partial_kernel<<<nslot, BLOCK, 0, stream>>>(input, target,
                                                     ws_pk, ws_s, ws_sx, ws_sy);
    dsnt_final_kernel<<<1, 256, 0, stream>>>(ws_pk, ws_s, ws_sx, ws_sy,
                                             out, n_maps);
}

// Round 10
// 131.458 us; speedup vs baseline: 1.0577x; 1.0577x over previous
//
#include <hip/hip_runtime.h>
#include <math.h>

// Problem: B=32, C=8, H=256, W=256. 256 independent (softmax-expectation +
// argmax) reductions over 65536-element fp32 heatmaps, then sum(ed)/B.
// 134 MB pure-READ traffic, zero reuse.
// Ladder so far: cached-both = 42 us (3.2 TB/s: 1.6 HBM + 1.6 L3);
// nt-both = ~35 us (R8, ~3.8 TB/s, allocation-cap bypassed); forced MLP
// null under BOTH policies (R5, R9). This round: HYBRID policy split --
// input via nt (HBM-direct service), target via cached loads (L3-resident
// service). If the L3-hit path and HBM-fetch path serve concurrently,
// the two 67 MB streams overlap: ~35 -> ~22-27 us.

constexpr int HW    = 256 * 256;       // elements per (b,c) heatmap
constexpr int BLOCK = 256;             // 4 waves
constexpr int SPLIT = 16;              // blocks per heatmap
constexpr int CHUNK4 = (HW / 4) / SPLIT;        // float4s per chunk = 1024
constexpr int ITERS  = CHUNK4 / BLOCK;          // float4s per thread = 4

typedef float vfloat4 __attribute__((ext_vector_type(4)));  // native vector

__global__ __launch_bounds__(BLOCK, 8) void dsnt_partial_kernel(
        const float* __restrict__ input,
        const float* __restrict__ target,
        unsigned long long* __restrict__ ws_pk,   // [nmap*SPLIT]
        float* __restrict__ ws_s,                 // [nmap*SPLIT]
        float* __restrict__ ws_sx,
        float* __restrict__ ws_sy)
{
    const int bc    = blockIdx.x >> 4;          // heatmap index
    const int chunk = blockIdx.x & (SPLIT - 1); // which sixteenth of it
    const int tid   = threadIdx.x;

    const vfloat4* __restrict__ in4 =
        reinterpret_cast<const vfloat4*>(input) + (size_t)bc * (HW / 4) + chunk * CHUNK4;
    const vfloat4* __restrict__ tg4 =
        reinterpret_cast<const vfloat4*>(target) + (size_t)bc * (HW / 4) + chunk * CHUNK4;

    // online accumulators (no max-subtraction needed: inputs ~ N(0,1),
    // exp() range [e^-6, e^6], sum ~1e5 -- safe in fp32; softmax is
    // shift-invariant so this matches the stabilized reference)
    float s = 0.f, sx = 0.f, sy = 0.f;
    float bv = -INFINITY;       // target argmax value
    int   bi = 0x7FFFFFFF;      // target argmax flat index (within heatmap)

    const int fbase = 4 * chunk * CHUNK4;        // chunk's flat base index

    #pragma unroll
    for (int i = 0; i < ITERS; ++i) {
        const int j = tid + i * BLOCK;           // float4 index within chunk
        // HYBRID: input non-temporal (HBM-direct, bypasses the allocation
        // cap); target cached (L3-resident service) -- two service paths.
        const vfloat4 v = __builtin_nontemporal_load(in4 + j);
        const vfloat4 t = tg4[j];
        const int f = fbase + 4 * j;             // flat element index
        // W=256: a float4 never crosses a row
        const float y  = (float)((f >> 8) + 1) * (1.0f / 256.0f);
        const float x0 = (float)((f & 255) + 1) * (1.0f / 256.0f);

        const float e0 = __expf(v.x);
        const float e1 = __expf(v.y);
        const float e2 = __expf(v.z);
        const float e3 = __expf(v.w);
        const float es = (e0 + e1) + (e2 + e3);
        s  += es;
        sy += es * y;
        sx += e0 * x0
            + e1 * (x0 + 1.0f / 256.0f)
            + e2 * (x0 + 2.0f / 256.0f)
            + e3 * (x0 + 3.0f / 256.0f);

        // argmax, first-occurrence tie-break (strict > keeps lowest f
        // within a thread since f is increasing)
        if (t.x > bv) { bv = t.x; bi = f; }
        if (t.y > bv) { bv = t.y; bi = f + 1; }
        if (t.z > bv) { bv = t.z; bi = f + 2; }
        if (t.w > bv) { bv = t.w; bi = f + 3; }
    }

    // pack (value, inverted index): target in [0,1) so float bits are
    // order-isomorphic; larger packed == larger value, ties -> smaller index
    unsigned long long pk =
        ((unsigned long long)__float_as_uint(bv) << 32) |
        (unsigned long long)(0xFFFFFFFFu - (unsigned)bi);

    // wave-level reduction (64 lanes)
    #pragma unroll
    for (int off = 32; off > 0; off >>= 1) {
        s  += __shfl_down(s, off);
        sx += __shfl_down(sx, off);
        sy += __shfl_down(sy, off);
        const unsigned long long opk = __shfl_down(pk, off);
        pk = (opk > pk) ? opk : pk;
    }

    // cross-wave reduction via LDS (4 waves)
    __shared__ float ls[4], lsx[4], lsy[4];
    __shared__ unsigned long long lpk[4];
    const int wave = tid >> 6;
    const int lane = tid & 63;
    if (lane == 0) {
        ls[wave]  = s;
        lsx[wave] = sx;
        lsy[wave] = sy;
        lpk[wave] = pk;
    }
    __syncthreads();

    if (tid == 0) {
        #pragma unroll
        for (int wv = 1; wv < 4; ++wv) {
            s  += ls[wv];
            sx += lsx[wv];
            sy += lsy[wv];
            pk = (lpk[wv] > pk) ? lpk[wv] : pk;
        }
        const int slot = blockIdx.x;   // == bc * SPLIT + chunk
        ws_s[slot]  = s;
        ws_sx[slot] = sx;
        ws_sy[slot] = sy;
        ws_pk[slot] = pk;
    }
}

// one block, 256 threads: thread bc combines its 16 chunks in fixed order
// (deterministic), computes ed, block-reduces, writes the scalar.
__global__ __launch_bounds__(256) void dsnt_final_kernel(
        const unsigned long long* __restrict__ ws_pk,
        const float* __restrict__ ws_s,
        const float* __restrict__ ws_sx,
        const float* __restrict__ ws_sy,
        float* __restrict__ out,
        int nmap)
{
    const int bc = threadIdx.x;
    float ed = 0.f;
    if (bc < nmap) {
        float s = 0.f, sx = 0.f, sy = 0.f;
        unsigned long long pk = 0ull;
        #pragma unroll
        for (int c = 0; c < SPLIT; ++c) {
            const int slot = bc * SPLIT + c;
            s  += ws_s[slot];
            sx += ws_sx[slot];
            sy += ws_sy[slot];
            const unsigned long long p = ws_pk[slot];
            pk = (p > pk) ? p : pk;
        }
        const unsigned bi = 0xFFFFFFFFu - (unsigned)(pk & 0xFFFFFFFFull);
        const float px = sx / s;
        const float py = sy / s;
        const float tx = (float)((bi & 255) + 1) * (1.0f / 256.0f);
        const float ty = (float)((bi >> 8) + 1) * (1.0f / 256.0f);
        const float dx = tx - px;
        const float dy = ty - py;
        ed = sqrtf(dx * dx + dy * dy);
    }

    // block reduction of ed over 256 threads
    #pragma unroll
    for (int off = 32; off > 0; off >>= 1)
        ed += __shfl_down(ed, off);

    __shared__ float led[4];
    const int wave = threadIdx.x >> 6;
    const int lane = threadIdx.x & 63;
    if (lane == 0) led[wave] = ed;
    __syncthreads();

    if (threadIdx.x == 0) {
        const float total = (led[0] + led[1]) + (led[2] + led[3]);
        out[0] = total * (1.0f / 32.0f);   // /B, B=32
    }
}

extern "C" void kernel_launch(void* const* d_in, const int* in_sizes, int n_in,
                              void* d_out, int out_size, void* d_ws, size_t ws_size,
                              hipStream_t stream) {
    const float* input  = (const float*)d_in[0];
    const float* target = (const float*)d_in[1];
    float* out = (float*)d_out;

    const int n_maps = in_sizes[0] / HW;   // B*C = 256
    const int nslot  = n_maps * SPLIT;     // 4096

    // workspace layout (all 8B-aligned; ~80 KB total):
    //   [0)        : u64 packed argmax, nslot
    //   [8*nslot)  : float s,  nslot
    //   [12*nslot) : float sx, nslot
    //   [16*nslot) : float sy, nslot
    unsigned long long* ws_pk = (unsigned long long*)d_ws;
    float* ws_s  = (float*)((char*)d_ws + (size_t)8  * nslot);
    float* ws_sx = (float*)((char*)d_ws + (size_t)12 * nslot);
    float* ws_sy = (float*)((char*)d_ws + (size_t)16 * nslot);

    // every (bc,chunk) slot is written unconditionally -> no memset needed;
    // final kernel overwrites the poisoned d_out directly.
    dsnt_partial_kernel<<<nslot, BLOCK, 0, stream>>>(input, target,
                                                     ws_pk, ws_s, ws_sx, ws_sy);
    dsnt_final_kernel<<<1, 256, 0, stream>>>(ws_pk, ws_s, ws_sx, ws_sy,
                                             out, n_maps);
}